// Round 15
// baseline (128.335 us; speedup 1.0000x reference)
//
#include <hip/hip_runtime.h>

// Problem constants
#define NNODES 64
#define HID 32
#define NFACT 3
#define NE 1024
#define NROWS (NE + NFACT)   // 1027
#define TPB 256
#define STR 36               // float row stride for xpp/qp
#define MAXTILES 128         // 16-edge tile capacity (true max = 124)
#define EPT (NE / TPB)       // 4 edges cached per thread

typedef short bf16x8 __attribute__((ext_vector_type(8)));
typedef float f32x2  __attribute__((ext_vector_type(2)));
typedef float f32x4v __attribute__((ext_vector_type(4)));
typedef float f32x16 __attribute__((ext_vector_type(16)));

// round-to-nearest-even two fp32 -> packed bf16x2 (lo | hi<<16)
__device__ __forceinline__ unsigned pack_bf2(float lo, float hi) {
    unsigned ul = __builtin_bit_cast(unsigned, lo);
    unsigned uh = __builtin_bit_cast(unsigned, hi);
    ul += 0x7fffu + ((ul >> 16) & 1u);
    uh += 0x7fffu + ((uh >> 16) & 1u);
    return (ul >> 16) | (uh & 0xffff0000u);
}
__device__ __forceinline__ short f2bf(float f) {
    unsigned u = __builtin_bit_cast(unsigned, f);
    u += 0x7fffu + ((u >> 16) & 1u);
    return (short)(u >> 16);
}
__device__ __forceinline__ float4 fma4(float a, float4 w, float4 c) {
    c.x = fmaf(a, w.x, c.x); c.y = fmaf(a, w.y, c.y);
    c.z = fmaf(a, w.z, c.z); c.w = fmaf(a, w.w, c.w);
    return c;
}
__device__ __forceinline__ f32x2 lo2(float4 v) { return f32x2{v.x, v.y}; }
__device__ __forceinline__ f32x2 hi2(float4 v) { return f32x2{v.z, v.w}; }
__device__ __forceinline__ f32x2 relu2(f32x2 v) {
    return __builtin_elementwise_max(v, f32x2{0.f, 0.f});
}

// R12 structure (best: 44.3us dispatch; in-block CSR, 16-edge tiles, pair-tiled
// 32x32x16 MFMA edge stage, MFMA head stage) + PACKED-F32 VALU (v_pk_add/fma/max)
// in the two biggest scalar-VALU slabs (stage-B h1, stage-C combine). R14 showed
// VALU (not DS) is the critical pipe: halving stage-B DS was neutral-to-negative
// while adding unpack VALU. pk-f32 halves VALU instructions for the same math.
//   pep packed: low12 = edge id (0xFFF = pad), bits12-17 = dst, bits18-23 = src
__global__ __launch_bounds__(TPB, 4) void critic_fused(
    const float* __restrict__ x,
    const float* __restrict__ edge_attr,
    const float* __restrict__ action,
    const int*   __restrict__ es,
    const int*   __restrict__ ed,
    const float* __restrict__ W1,
    const float* __restrict__ b1,
    const float* __restrict__ W2,
    const float* __restrict__ b2,
    const float* __restrict__ Wl,
    const float* __restrict__ bl,
    const float* __restrict__ Wv,
    const float* __restrict__ bv,
    float* __restrict__ out)
{
    const int b    = blockIdx.x;
    const int tid  = threadIdx.x;
    const int lane = tid & 63;
    const int wv   = tid >> 6;
    const int quad = lane >> 4;
    const int m16  = lane & 15;
    const int kh   = quad * 8;

    __shared__ __align__(16) float4 xs4[NNODES];
    __shared__ __align__(16) float  xpp[NNODES * STR];
    __shared__ __align__(16) float  qp0[NNODES * STR];   // Q1 then P1
    __shared__ __align__(16) float  qp1[NNODES * STR];   // Q2 then P2
    __shared__ __align__(16) float  W1s[10 * HID];
    __shared__ float  b1s[HID];
    __shared__ float  wred[TPB / 64];
    // CSR tables (built per block, 16-edge tiles)
    __shared__ int    sdeg[NNODES], soff[NNODES], scnt[NNODES];
    __shared__ int    tns[MAXTILES];
    __shared__ int    pep[MAXTILES * 16];
    __shared__ int    snt;

    // ---- Stage A: stage x + W1, zero xpp, init CSR tables ----
    if (tid < NNODES) { xs4[tid] = ((const float4*)x)[b * NNODES + tid]; sdeg[tid] = 0; scnt[tid] = 0; }
    if (tid < 80) ((float4*)W1s)[tid] = ((const float4*)W1)[tid];
    if (tid < HID) b1s[tid] = b1[tid];
    if (tid < MAXTILES) tns[tid] = 0;
#pragma unroll
    for (int i = 0; i < MAXTILES * 16 / TPB; i++) pep[tid + i * TPB] = 0xFFF;  // pad, node 0
#pragma unroll 1
    for (int i = tid; i < NNODES * STR; i += TPB) xpp[i] = 0.0f;

    // cache this thread's 4 edges in registers (coalesced global reads)
    int ces[EPT], ced[EPT];
#pragma unroll
    for (int i = 0; i < EPT; i++) {
        ces[i] = es[tid + i * TPB];
        ced[i] = ed[tid + i * TPB];
    }
    __syncthreads();

    // ---- CSR count + Stage Q (independent; co-scheduled to hide latency) ----
#pragma unroll
    for (int i = 0; i < EPT; i++) atomicAdd(&sdeg[ces[i]], 1);
    {
        const int n  = lane;
        const int k0 = wv * 8;
        const float4 xv = xs4[n];
        const float4* b1v = (const float4*)&b1s[k0];
        float4 q1a = b1v[0], q1b = b1v[1];
        float4 q2a = make_float4(0.f, 0.f, 0.f, 0.f), q2b = q2a;
#pragma unroll 1
        for (int i = 0; i < 4; i++) {
            const float xi = (i == 0) ? xv.x : (i == 1) ? xv.y : (i == 2) ? xv.z : xv.w;
            const float4* wa = (const float4*)&W1s[i * HID + k0];
            const float4* wb = (const float4*)&W1s[(4 + i) * HID + k0];
            q1a = fma4(xi, wa[0], q1a); q1b = fma4(xi, wa[1], q1b);
            q2a = fma4(xi, wb[0], q2a); q2b = fma4(xi, wb[1], q2b);
        }
        float4* q1w = (float4*)&qp0[n * STR + k0];
        float4* q2w = (float4*)&qp1[n * STR + k0];
        q1w[0] = q1a; q1w[1] = q1b;
        q2w[0] = q2a; q2w[1] = q2b;
    }
    __syncthreads();

    // ---- CSR scan (wave 0) + tile-node fill ----
    if (tid < NNODES) {
        const int cnt = (sdeg[tid] + 15) >> 4;
        int scan = cnt;
#pragma unroll
        for (int o = 1; o < 64; o <<= 1) {
            const int v = __shfl_up(scan, o);
            if (tid >= o) scan += v;
        }
        const int base = scan - cnt;
        soff[tid] = base;
        if (tid == NNODES - 1) snt = scan;           // ~90-96, <=124
#pragma unroll 1
        for (int j = 0; j < cnt; j++) tns[base + j] = tid;
    }
    __syncthreads();

    // ---- CSR scatter (cached edges) ----
#pragma unroll
    for (int i = 0; i < EPT; i++) {
        const int n = ces[i];
        const int idx = atomicAdd(&scnt[n], 1);
        pep[soff[n] * 16 + idx] = (tid + i * TPB) | (ced[i] << 12) | (n << 18);
    }
    __syncthreads();

    // ---- Stage B: pair-tiled MFMA edge messages (32 edges / 2 nodes per iter) ----
    {
        const float2* ea2 = (const float2*)edge_attr + (size_t)b * NE;
        const int NW  = TPB / 64;
        const int klo = (lane >> 5) * 8;      // K-slice base (0 or 8)
        const int n32 = lane & 31;

        // W1 rows 8,9 at k slices, pre-split to f32x2
        const float4* w8l = (const float4*)&W1s[8 * HID + klo];
        const float4* w8h = (const float4*)&W1s[8 * HID + 16 + klo];
        const float4* w9l = (const float4*)&W1s[9 * HID + klo];
        const float4* w9h = (const float4*)&W1s[9 * HID + 16 + klo];
        const f32x2 w8_0 = lo2(w8l[0]), w8_1 = hi2(w8l[0]), w8_2 = lo2(w8l[1]), w8_3 = hi2(w8l[1]);
        const f32x2 w8_4 = lo2(w8h[0]), w8_5 = hi2(w8h[0]), w8_6 = lo2(w8h[1]), w8_7 = hi2(w8h[1]);
        const f32x2 w9_0 = lo2(w9l[0]), w9_1 = hi2(w9l[0]), w9_2 = lo2(w9l[1]), w9_3 = hi2(w9l[1]);
        const f32x2 w9_4 = lo2(w9h[0]), w9_5 = hi2(w9h[0]), w9_6 = lo2(w9h[1]), w9_7 = hi2(w9h[1]);

        bf16x8 bfA, bfB;   // W2 B-frags: B[k][n32], K-halves 0..15 / 16..31
#pragma unroll
        for (int j = 0; j < 8; j++) {
            bfA[j] = f2bf(W2[(klo + j) * HID + n32]);
            bfB[j] = f2bf(W2[(16 + klo + j) * HID + n32]);
        }

        const int np = (snt + 1) >> 1;

#pragma unroll 1
        for (int p = wv; p < np; p += NW) {
            const int raw = pep[p * 32 + n32];        // edge slot = window row n32
            const int tA  = tns[2 * p];
            const int tB  = tns[2 * p + 1];
            const int e    = raw & 0xFFF;
            const bool pad = (e == 0xFFF);
            const int d0   = (raw >> 12) & 63;
            const int nd   = (raw >> 18) & 63;        // src node of MY edge
            const float2 ea = ea2[pad ? 0 : e];
            const f32x2 eax = {ea.x, ea.x};
            const f32x2 eay = {ea.y, ea.y};

            const float4* A1 = (const float4*)&qp0[nd * STR + klo];
            const float4* A2 = (const float4*)&qp0[nd * STR + 16 + klo];
            const float4* G1 = (const float4*)&qp1[d0 * STR + klo];
            const float4* G2 = (const float4*)&qp1[d0 * STR + 16 + klo];
            const float4 a0 = A1[0], a1 = A1[1], a2 = A2[0], a3 = A2[1];
            const float4 g0 = G1[0], g1 = G1[1], g2 = G2[0], g3 = G2[1];

            // packed-f32 h1: 4 pk-ops per 2 values (v_pk_add/v_pk_fma/v_pk_max)
            const f32x2 hA0 = relu2(lo2(a0) + lo2(g0) + eax * w8_0 + eay * w9_0);
            const f32x2 hA1 = relu2(hi2(a0) + hi2(g0) + eax * w8_1 + eay * w9_1);
            const f32x2 hA2 = relu2(lo2(a1) + lo2(g1) + eax * w8_2 + eay * w9_2);
            const f32x2 hA3 = relu2(hi2(a1) + hi2(g1) + eax * w8_3 + eay * w9_3);
            const f32x2 hB0 = relu2(lo2(a2) + lo2(g2) + eax * w8_4 + eay * w9_4);
            const f32x2 hB1 = relu2(hi2(a2) + hi2(g2) + eax * w8_5 + eay * w9_5);
            const f32x2 hB2 = relu2(lo2(a3) + lo2(g3) + eax * w8_6 + eay * w9_6);
            const f32x2 hB3 = relu2(hi2(a3) + hi2(g3) + eax * w8_7 + eay * w9_7);

            uint4 pkA, pkB;
            pkA.x = pad ? 0u : pack_bf2(hA0.x, hA0.y);
            pkA.y = pad ? 0u : pack_bf2(hA1.x, hA1.y);
            pkA.z = pad ? 0u : pack_bf2(hA2.x, hA2.y);
            pkA.w = pad ? 0u : pack_bf2(hA3.x, hA3.y);
            pkB.x = pad ? 0u : pack_bf2(hB0.x, hB0.y);
            pkB.y = pad ? 0u : pack_bf2(hB1.x, hB1.y);
            pkB.z = pad ? 0u : pack_bf2(hB2.x, hB2.y);
            pkB.w = pad ? 0u : pack_bf2(hB3.x, hB3.y);
            const bf16x8 afA = __builtin_bit_cast(bf16x8, pkA);
            const bf16x8 afB = __builtin_bit_cast(bf16x8, pkB);

            f32x16 c;
#pragma unroll
            for (int j = 0; j < 16; j++) c[j] = 0.0f;
            c = __builtin_amdgcn_mfma_f32_32x32x16_bf16(afA, bfA, c, 0, 0, 0);
            c = __builtin_amdgcn_mfma_f32_32x32x16_bf16(afB, bfB, c, 0, 0, 0);

            // C: col=lane&31, row=(reg&3)+8*(reg>>2)+4*(lane>>5).
            float sA = ((c[0] + c[1]) + (c[2] + c[3])) + ((c[4] + c[5]) + (c[6] + c[7]));
            float sB = ((c[8] + c[9]) + (c[10] + c[11])) + ((c[12] + c[13]) + (c[14] + c[15]));
            sA += __shfl_xor(sA, 32);
            sB += __shfl_xor(sB, 32);
            const int   nst = (lane < 32) ? tA : tB;
            const float sv  = (lane < 32) ? sA : sB;
            atomicAdd(&xpp[nst * STR + n32], sv);     // full wave, contiguous per node
        }
    }
    __syncthreads();

    // ---- Stage-P constants (loaded after B to keep stage-B VGPR peak low) ----
    bf16x8 bP1a, bP1b, bP2a, bP2b;    // Wl[4:36] / Wl[40:72] B-fragments, col halves
#pragma unroll
    for (int j = 0; j < 8; j++) {
        bP1a[j] = f2bf(Wl[(4 + kh + j) * HID + m16]);
        bP1b[j] = f2bf(Wl[(4 + kh + j) * HID + 16 + m16]);
        bP2a[j] = f2bf(Wl[(40 + kh + j) * HID + m16]);
        bP2b[j] = f2bf(Wl[(40 + kh + j) * HID + 16 + m16]);
    }
    float wx1a[4], wx1b[4], wx2a[4], wx2b[4];   // x-part weights (K=4 tail)
#pragma unroll
    for (int i = 0; i < 4; i++) {
        wx1a[i] = Wl[i * HID + m16];
        wx1b[i] = Wl[i * HID + 16 + m16];
        wx2a[i] = Wl[(36 + i) * HID + m16];
        wx2b[i] = Wl[(36 + i) * HID + 16 + m16];
    }
    const float blca = bl[m16], blcb = bl[16 + m16];
    float b2k[8];
#pragma unroll
    for (int j = 0; j < 8; j++) b2k[j] = b2[kh + j];
    const int   mrow = wv * 16 + m16;                // A-row this lane owns in stage P
    const float dn   = (float)sdeg[mrow];

    // ---- Stage P: head projections via MFMA ----
    {
        const float4* xr = (const float4*)&xpp[mrow * STR + kh];
        float4 x0 = xr[0], x1 = xr[1];
        x0.x = fmaf(dn, b2k[0], x0.x); x0.y = fmaf(dn, b2k[1], x0.y);
        x0.z = fmaf(dn, b2k[2], x0.z); x0.w = fmaf(dn, b2k[3], x0.w);
        x1.x = fmaf(dn, b2k[4], x1.x); x1.y = fmaf(dn, b2k[5], x1.y);
        x1.z = fmaf(dn, b2k[6], x1.z); x1.w = fmaf(dn, b2k[7], x1.w);
        uint4 packed;
        packed.x = pack_bf2(x0.x, x0.y);
        packed.y = pack_bf2(x0.z, x0.w);
        packed.z = pack_bf2(x1.x, x1.y);
        packed.w = pack_bf2(x1.z, x1.w);
        const bf16x8 af = __builtin_bit_cast(bf16x8, packed);

        f32x4v c1a, c1b, c2a, c2b;
#pragma unroll
        for (int r = 0; r < 4; r++) {
            const float4 xv = xs4[wv * 16 + quad * 4 + r];
            float a0 = blca, a1 = blcb, a2 = 0.f, a3 = 0.f;
#pragma unroll
            for (int i = 0; i < 4; i++) {
                const float xi = (i == 0) ? xv.x : (i == 1) ? xv.y : (i == 2) ? xv.z : xv.w;
                a0 = fmaf(xi, wx1a[i], a0);
                a1 = fmaf(xi, wx1b[i], a1);
                a2 = fmaf(xi, wx2a[i], a2);
                a3 = fmaf(xi, wx2b[i], a3);
            }
            c1a[r] = a0; c1b[r] = a1; c2a[r] = a2; c2b[r] = a3;
        }
        c1a = __builtin_amdgcn_mfma_f32_16x16x32_bf16(af, bP1a, c1a, 0, 0, 0);
        c1b = __builtin_amdgcn_mfma_f32_16x16x32_bf16(af, bP1b, c1b, 0, 0, 0);
        c2a = __builtin_amdgcn_mfma_f32_16x16x32_bf16(af, bP2a, c2a, 0, 0, 0);
        c2b = __builtin_amdgcn_mfma_f32_16x16x32_bf16(af, bP2b, c2b, 0, 0, 0);

        // C layout: row = wv*16 + quad*4 + r, col = m16 / 16+m16
#pragma unroll
        for (int r = 0; r < 4; r++) {
            const int row = wv * 16 + quad * 4 + r;
            qp0[row * STR + m16]      = c1a[r];
            qp0[row * STR + 16 + m16] = c1b[r];
            qp1[row * STR + m16]      = c2a[r];
            qp1[row * STR + 16 + m16] = c2b[r];
        }
    }
    __syncthreads();

    // ---- Stage C: per-row combine + value head (packed-f32) ----
    float vsum = 0.0f;
    {
        const float* actb = action + (size_t)b * NROWS;
        const float bvv = bv[0];
        const f32x2* w72v = (const f32x2*)(Wl + 72 * HID);  // uniform -> s_load
        const f32x2* wvv  = (const f32x2*)Wv;
#pragma unroll 1
        for (int i = 0; i < 4; i++) {
            const int na = ces[i], nb = ced[i];             // cached edge endpoints
            const float a = actb[tid + i * TPB];
            const f32x2 av = {a, a};
            const float4* p1v = (const float4*)&qp0[na * STR];
            const float4* p2v = (const float4*)&qp1[nb * STR];
            f32x2 vacc = {0.f, 0.f};
#pragma unroll 2
            for (int q = 0; q < 8; q++) {
                const float4 pa = p1v[q], pb = p2v[q];
                const f32x2 rL = relu2(lo2(pa) + lo2(pb) + av * w72v[2 * q]);
                const f32x2 rH = relu2(hi2(pa) + hi2(pb) + av * w72v[2 * q + 1]);
                vacc += rL * wvv[2 * q] + rH * wvv[2 * q + 1];
            }
            vsum += bvv + vacc.x + vacc.y;
        }
        // factory rows 1024..1026 (na == nb)
        if (tid < NFACT) {
            const int r = NE + tid;
            const int na = NNODES - NFACT + tid;
            const float a = actb[r];
            const f32x2 av = {a, a};
            const float4* p1v = (const float4*)&qp0[na * STR];
            const float4* p2v = (const float4*)&qp1[na * STR];
            f32x2 vacc = {0.f, 0.f};
#pragma unroll 1
            for (int q = 0; q < 8; q++) {
                const float4 pa = p1v[q], pb = p2v[q];
                const f32x2 rL = relu2(lo2(pa) + lo2(pb) + av * w72v[2 * q]);
                const f32x2 rH = relu2(hi2(pa) + hi2(pb) + av * w72v[2 * q + 1]);
                vacc += rL * wvv[2 * q] + rH * wvv[2 * q + 1];
            }
            vsum += bvv + vacc.x + vacc.y;
        }
    }

    // ---- block reduction ----
#pragma unroll
    for (int off = 32; off > 0; off >>= 1)
        vsum += __shfl_down(vsum, off, 64);
    if ((tid & 63) == 0) wred[tid >> 6] = vsum;
    __syncthreads();
    if (tid == 0) {
        float t = 0.0f;
#pragma unroll
        for (int w = 0; w < TPB / 64; w++) t += wred[w];
        out[b] = t;
    }
}

extern "C" void kernel_launch(void* const* d_in, const int* in_sizes, int n_in,
                              void* d_out, int out_size, void* d_ws, size_t ws_size,
                              hipStream_t stream) {
    const float* x         = (const float*)d_in[0];
    const float* edge_attr = (const float*)d_in[2];
    const float* action    = (const float*)d_in[3];
    const int*   es        = (const int*)d_in[4];
    const int*   ed        = (const int*)d_in[5];
    const float* W1        = (const float*)d_in[6];
    const float* b1        = (const float*)d_in[7];
    const float* W2        = (const float*)d_in[8];
    const float* b2        = (const float*)d_in[9];
    const float* Wl        = (const float*)d_in[10];
    const float* bl        = (const float*)d_in[11];
    const float* Wv        = (const float*)d_in[12];
    const float* bv        = (const float*)d_in[13];
    float* out = (float*)d_out;

    critic_fused<<<dim3(out_size), dim3(TPB), 0, stream>>>(
        x, edge_attr, action, es, ed, W1, b1, W2, b2, Wl, bl, Wv, bv, out);
}

// Round 16
// 126.836 us; speedup vs baseline: 1.0118x; 1.0118x over previous
//
#include <hip/hip_runtime.h>

// Problem constants
#define NNODES 64
#define HID 32
#define NFACT 3
#define NE 1024
#define NROWS (NE + NFACT)   // 1027
#define TPB 256
#define STR 36               // float row stride for xpp/qp
#define MAXTILES 128         // 16-edge tile capacity (true max = 124)
#define EPT (NE / TPB)       // 4 edges cached per thread

typedef short bf16x8 __attribute__((ext_vector_type(8)));
typedef float f32x2  __attribute__((ext_vector_type(2)));
typedef float f32x4v __attribute__((ext_vector_type(4)));
typedef float f32x16 __attribute__((ext_vector_type(16)));

// round-to-nearest-even two fp32 -> packed bf16x2 (lo | hi<<16)
__device__ __forceinline__ unsigned pack_bf2(float lo, float hi) {
    unsigned ul = __builtin_bit_cast(unsigned, lo);
    unsigned uh = __builtin_bit_cast(unsigned, hi);
    ul += 0x7fffu + ((ul >> 16) & 1u);
    uh += 0x7fffu + ((uh >> 16) & 1u);
    return (ul >> 16) | (uh & 0xffff0000u);
}
__device__ __forceinline__ short f2bf(float f) {
    unsigned u = __builtin_bit_cast(unsigned, f);
    u += 0x7fffu + ((u >> 16) & 1u);
    return (short)(u >> 16);
}
__device__ __forceinline__ float4 fma4(float a, float4 w, float4 c) {
    c.x = fmaf(a, w.x, c.x); c.y = fmaf(a, w.y, c.y);
    c.z = fmaf(a, w.z, c.z); c.w = fmaf(a, w.w, c.w);
    return c;
}
__device__ __forceinline__ f32x2 lo2(float4 v) { return f32x2{v.x, v.y}; }
__device__ __forceinline__ f32x2 hi2(float4 v) { return f32x2{v.z, v.w}; }
__device__ __forceinline__ f32x2 relu2(f32x2 v) {
    return __builtin_elementwise_max(v, f32x2{0.f, 0.f});
}

// R15 base (in-block CSR, pair-tiled 32x32x16 MFMA edge stage, MFMA head, pk-f32
// VALU) + ILP against the ~35% dependency-stall residual: stage-B pep preloaded
// to registers (kills the dependent LDS level per iteration; loop fully unrolled
// with wave-uniform guard so the array stays in VGPRs), stage-C 2-row interleave
// (2 independent gather chains). R14/R15 proved DS and VALU widths are not the
// binding constraint at fixed 16 waves/CU; latency chains are the target.
//   pep packed: low12 = edge id (0xFFF = pad), bits12-17 = dst, bits18-23 = src
__global__ __launch_bounds__(TPB, 4) void critic_fused(
    const float* __restrict__ x,
    const float* __restrict__ edge_attr,
    const float* __restrict__ action,
    const int*   __restrict__ es,
    const int*   __restrict__ ed,
    const float* __restrict__ W1,
    const float* __restrict__ b1,
    const float* __restrict__ W2,
    const float* __restrict__ b2,
    const float* __restrict__ Wl,
    const float* __restrict__ bl,
    const float* __restrict__ Wv,
    const float* __restrict__ bv,
    float* __restrict__ out)
{
    const int b    = blockIdx.x;
    const int tid  = threadIdx.x;
    const int lane = tid & 63;
    const int wv   = tid >> 6;
    const int quad = lane >> 4;
    const int m16  = lane & 15;
    const int kh   = quad * 8;

    __shared__ __align__(16) float4 xs4[NNODES];
    __shared__ __align__(16) float  xpp[NNODES * STR];
    __shared__ __align__(16) float  qp0[NNODES * STR];   // Q1 then P1
    __shared__ __align__(16) float  qp1[NNODES * STR];   // Q2 then P2
    __shared__ __align__(16) float  W1s[10 * HID];
    __shared__ float  b1s[HID];
    __shared__ float  wred[TPB / 64];
    // CSR tables (built per block, 16-edge tiles)
    __shared__ int    sdeg[NNODES], soff[NNODES], scnt[NNODES];
    __shared__ int    tns[MAXTILES];
    __shared__ int    pep[MAXTILES * 16];
    __shared__ int    snt;

    // ---- Stage A: stage x + W1, zero xpp, init CSR tables ----
    if (tid < NNODES) { xs4[tid] = ((const float4*)x)[b * NNODES + tid]; sdeg[tid] = 0; scnt[tid] = 0; }
    if (tid < 80) ((float4*)W1s)[tid] = ((const float4*)W1)[tid];
    if (tid < HID) b1s[tid] = b1[tid];
    if (tid < MAXTILES) tns[tid] = 0;
#pragma unroll
    for (int i = 0; i < MAXTILES * 16 / TPB; i++) pep[tid + i * TPB] = 0xFFF;  // pad, node 0
#pragma unroll 1
    for (int i = tid; i < NNODES * STR; i += TPB) xpp[i] = 0.0f;

    // cache this thread's 4 edges in registers (coalesced global reads)
    int ces[EPT], ced[EPT];
#pragma unroll
    for (int i = 0; i < EPT; i++) {
        ces[i] = es[tid + i * TPB];
        ced[i] = ed[tid + i * TPB];
    }
    __syncthreads();

    // ---- CSR count + Stage Q (independent; co-scheduled to hide latency) ----
#pragma unroll
    for (int i = 0; i < EPT; i++) atomicAdd(&sdeg[ces[i]], 1);
    {
        const int n  = lane;
        const int k0 = wv * 8;
        const float4 xv = xs4[n];
        const float4* b1v = (const float4*)&b1s[k0];
        float4 q1a = b1v[0], q1b = b1v[1];
        float4 q2a = make_float4(0.f, 0.f, 0.f, 0.f), q2b = q2a;
#pragma unroll 1
        for (int i = 0; i < 4; i++) {
            const float xi = (i == 0) ? xv.x : (i == 1) ? xv.y : (i == 2) ? xv.z : xv.w;
            const float4* wa = (const float4*)&W1s[i * HID + k0];
            const float4* wb = (const float4*)&W1s[(4 + i) * HID + k0];
            q1a = fma4(xi, wa[0], q1a); q1b = fma4(xi, wa[1], q1b);
            q2a = fma4(xi, wb[0], q2a); q2b = fma4(xi, wb[1], q2b);
        }
        float4* q1w = (float4*)&qp0[n * STR + k0];
        float4* q2w = (float4*)&qp1[n * STR + k0];
        q1w[0] = q1a; q1w[1] = q1b;
        q2w[0] = q2a; q2w[1] = q2b;
    }
    __syncthreads();

    // ---- CSR scan (wave 0) + tile-node fill ----
    if (tid < NNODES) {
        const int cnt = (sdeg[tid] + 15) >> 4;
        int scan = cnt;
#pragma unroll
        for (int o = 1; o < 64; o <<= 1) {
            const int v = __shfl_up(scan, o);
            if (tid >= o) scan += v;
        }
        const int base = scan - cnt;
        soff[tid] = base;
        if (tid == NNODES - 1) snt = scan;           // ~90-96, <=124
#pragma unroll 1
        for (int j = 0; j < cnt; j++) tns[base + j] = tid;
    }
    __syncthreads();

    // ---- CSR scatter (cached edges) ----
#pragma unroll
    for (int i = 0; i < EPT; i++) {
        const int n = ces[i];
        const int idx = atomicAdd(&scnt[n], 1);
        pep[soff[n] * 16 + idx] = (tid + i * TPB) | (ced[i] << 12) | (n << 18);
    }
    __syncthreads();

    // ---- Stage B: pair-tiled MFMA edge messages; pep preloaded to registers ----
    {
        const float2* ea2 = (const float2*)edge_attr + (size_t)b * NE;
        const int NW  = TPB / 64;
        const int klo = (lane >> 5) * 8;      // K-slice base (0 or 8)
        const int n32 = lane & 31;

        // W1 rows 8,9 at k slices, pre-split to f32x2
        const float4* w8l = (const float4*)&W1s[8 * HID + klo];
        const float4* w8h = (const float4*)&W1s[8 * HID + 16 + klo];
        const float4* w9l = (const float4*)&W1s[9 * HID + klo];
        const float4* w9h = (const float4*)&W1s[9 * HID + 16 + klo];
        const f32x2 w8_0 = lo2(w8l[0]), w8_1 = hi2(w8l[0]), w8_2 = lo2(w8l[1]), w8_3 = hi2(w8l[1]);
        const f32x2 w8_4 = lo2(w8h[0]), w8_5 = hi2(w8h[0]), w8_6 = lo2(w8h[1]), w8_7 = hi2(w8h[1]);
        const f32x2 w9_0 = lo2(w9l[0]), w9_1 = hi2(w9l[0]), w9_2 = lo2(w9l[1]), w9_3 = hi2(w9l[1]);
        const f32x2 w9_4 = lo2(w9h[0]), w9_5 = hi2(w9h[0]), w9_6 = lo2(w9h[1]), w9_7 = hi2(w9h[1]);

        bf16x8 bfA, bfB;   // W2 B-frags: B[k][n32], K-halves 0..15 / 16..31
#pragma unroll
        for (int j = 0; j < 8; j++) {
            bfA[j] = f2bf(W2[(klo + j) * HID + n32]);
            bfB[j] = f2bf(W2[(16 + klo + j) * HID + n32]);
        }

        const int np = (snt + 1) >> 1;        // pair-windows (<=62); wave-uniform

        // Preload ALL pep slots this lane will touch (out-of-range -> 0xFFF pad,
        // safe: pep has MAXTILES/2 = 64 windows, max index wv+15*4 = 63).
        int raws[16];
#pragma unroll
        for (int i = 0; i < 16; i++)
            raws[i] = pep[(wv + i * NW) * 32 + n32];

#pragma unroll
        for (int i = 0; i < 16; i++) {
            const int p = wv + i * NW;
            if (p < np) {                      // wave-uniform guard (s_cbranch skip)
                const int raw = raws[i];
                const int tA  = tns[2 * p];
                const int tB  = tns[2 * p + 1];
                const int e    = raw & 0xFFF;
                const bool pad = (e == 0xFFF);
                const int d0   = (raw >> 12) & 63;
                const int nd   = (raw >> 18) & 63;        // src node of MY edge
                const float2 ea = ea2[pad ? 0 : e];
                const f32x2 eax = {ea.x, ea.x};
                const f32x2 eay = {ea.y, ea.y};

                const float4* A1 = (const float4*)&qp0[nd * STR + klo];
                const float4* A2 = (const float4*)&qp0[nd * STR + 16 + klo];
                const float4* G1 = (const float4*)&qp1[d0 * STR + klo];
                const float4* G2 = (const float4*)&qp1[d0 * STR + 16 + klo];
                const float4 a0 = A1[0], a1 = A1[1], a2 = A2[0], a3 = A2[1];
                const float4 g0 = G1[0], g1 = G1[1], g2 = G2[0], g3 = G2[1];

                // packed-f32 h1 (v_pk_add/fma/max)
                const f32x2 hA0 = relu2(lo2(a0) + lo2(g0) + eax * w8_0 + eay * w9_0);
                const f32x2 hA1 = relu2(hi2(a0) + hi2(g0) + eax * w8_1 + eay * w9_1);
                const f32x2 hA2 = relu2(lo2(a1) + lo2(g1) + eax * w8_2 + eay * w9_2);
                const f32x2 hA3 = relu2(hi2(a1) + hi2(g1) + eax * w8_3 + eay * w9_3);
                const f32x2 hB0 = relu2(lo2(a2) + lo2(g2) + eax * w8_4 + eay * w9_4);
                const f32x2 hB1 = relu2(hi2(a2) + hi2(g2) + eax * w8_5 + eay * w9_5);
                const f32x2 hB2 = relu2(lo2(a3) + lo2(g3) + eax * w8_6 + eay * w9_6);
                const f32x2 hB3 = relu2(hi2(a3) + hi2(g3) + eax * w8_7 + eay * w9_7);

                uint4 pkA, pkB;
                pkA.x = pad ? 0u : pack_bf2(hA0.x, hA0.y);
                pkA.y = pad ? 0u : pack_bf2(hA1.x, hA1.y);
                pkA.z = pad ? 0u : pack_bf2(hA2.x, hA2.y);
                pkA.w = pad ? 0u : pack_bf2(hA3.x, hA3.y);
                pkB.x = pad ? 0u : pack_bf2(hB0.x, hB0.y);
                pkB.y = pad ? 0u : pack_bf2(hB1.x, hB1.y);
                pkB.z = pad ? 0u : pack_bf2(hB2.x, hB2.y);
                pkB.w = pad ? 0u : pack_bf2(hB3.x, hB3.y);
                const bf16x8 afA = __builtin_bit_cast(bf16x8, pkA);
                const bf16x8 afB = __builtin_bit_cast(bf16x8, pkB);

                f32x16 c;
#pragma unroll
                for (int j = 0; j < 16; j++) c[j] = 0.0f;
                c = __builtin_amdgcn_mfma_f32_32x32x16_bf16(afA, bfA, c, 0, 0, 0);
                c = __builtin_amdgcn_mfma_f32_32x32x16_bf16(afB, bfB, c, 0, 0, 0);

                // C: col=lane&31, row=(reg&3)+8*(reg>>2)+4*(lane>>5).
                float sA = ((c[0] + c[1]) + (c[2] + c[3])) + ((c[4] + c[5]) + (c[6] + c[7]));
                float sB = ((c[8] + c[9]) + (c[10] + c[11])) + ((c[12] + c[13]) + (c[14] + c[15]));
                sA += __shfl_xor(sA, 32);
                sB += __shfl_xor(sB, 32);
                const int   nst = (lane < 32) ? tA : tB;
                const float sv  = (lane < 32) ? sA : sB;
                atomicAdd(&xpp[nst * STR + n32], sv);   // full wave, contiguous per node
            }
        }
    }
    __syncthreads();

    // ---- Stage-P constants (loaded after B to keep stage-B VGPR peak low) ----
    bf16x8 bP1a, bP1b, bP2a, bP2b;    // Wl[4:36] / Wl[40:72] B-fragments, col halves
#pragma unroll
    for (int j = 0; j < 8; j++) {
        bP1a[j] = f2bf(Wl[(4 + kh + j) * HID + m16]);
        bP1b[j] = f2bf(Wl[(4 + kh + j) * HID + 16 + m16]);
        bP2a[j] = f2bf(Wl[(40 + kh + j) * HID + m16]);
        bP2b[j] = f2bf(Wl[(40 + kh + j) * HID + 16 + m16]);
    }
    float wx1a[4], wx1b[4], wx2a[4], wx2b[4];   // x-part weights (K=4 tail)
#pragma unroll
    for (int i = 0; i < 4; i++) {
        wx1a[i] = Wl[i * HID + m16];
        wx1b[i] = Wl[i * HID + 16 + m16];
        wx2a[i] = Wl[(36 + i) * HID + m16];
        wx2b[i] = Wl[(36 + i) * HID + 16 + m16];
    }
    const float blca = bl[m16], blcb = bl[16 + m16];
    float b2k[8];
#pragma unroll
    for (int j = 0; j < 8; j++) b2k[j] = b2[kh + j];
    const int   mrow = wv * 16 + m16;                // A-row this lane owns in stage P
    const float dn   = (float)sdeg[mrow];

    // ---- Stage P: head projections via MFMA ----
    {
        const float4* xr = (const float4*)&xpp[mrow * STR + kh];
        float4 x0 = xr[0], x1 = xr[1];
        x0.x = fmaf(dn, b2k[0], x0.x); x0.y = fmaf(dn, b2k[1], x0.y);
        x0.z = fmaf(dn, b2k[2], x0.z); x0.w = fmaf(dn, b2k[3], x0.w);
        x1.x = fmaf(dn, b2k[4], x1.x); x1.y = fmaf(dn, b2k[5], x1.y);
        x1.z = fmaf(dn, b2k[6], x1.z); x1.w = fmaf(dn, b2k[7], x1.w);
        uint4 packed;
        packed.x = pack_bf2(x0.x, x0.y);
        packed.y = pack_bf2(x0.z, x0.w);
        packed.z = pack_bf2(x1.x, x1.y);
        packed.w = pack_bf2(x1.z, x1.w);
        const bf16x8 af = __builtin_bit_cast(bf16x8, packed);

        f32x4v c1a, c1b, c2a, c2b;
#pragma unroll
        for (int r = 0; r < 4; r++) {
            const float4 xv = xs4[wv * 16 + quad * 4 + r];
            float a0 = blca, a1 = blcb, a2 = 0.f, a3 = 0.f;
#pragma unroll
            for (int i = 0; i < 4; i++) {
                const float xi = (i == 0) ? xv.x : (i == 1) ? xv.y : (i == 2) ? xv.z : xv.w;
                a0 = fmaf(xi, wx1a[i], a0);
                a1 = fmaf(xi, wx1b[i], a1);
                a2 = fmaf(xi, wx2a[i], a2);
                a3 = fmaf(xi, wx2b[i], a3);
            }
            c1a[r] = a0; c1b[r] = a1; c2a[r] = a2; c2b[r] = a3;
        }
        c1a = __builtin_amdgcn_mfma_f32_16x16x32_bf16(af, bP1a, c1a, 0, 0, 0);
        c1b = __builtin_amdgcn_mfma_f32_16x16x32_bf16(af, bP1b, c1b, 0, 0, 0);
        c2a = __builtin_amdgcn_mfma_f32_16x16x32_bf16(af, bP2a, c2a, 0, 0, 0);
        c2b = __builtin_amdgcn_mfma_f32_16x16x32_bf16(af, bP2b, c2b, 0, 0, 0);

        // C layout: row = wv*16 + quad*4 + r, col = m16 / 16+m16
#pragma unroll
        for (int r = 0; r < 4; r++) {
            const int row = wv * 16 + quad * 4 + r;
            qp0[row * STR + m16]      = c1a[r];
            qp0[row * STR + 16 + m16] = c1b[r];
            qp1[row * STR + m16]      = c2a[r];
            qp1[row * STR + 16 + m16] = c2b[r];
        }
    }
    __syncthreads();

    // ---- Stage C: per-row combine + value head (pk-f32, 2-row interleave) ----
    float vsum = 0.0f;
    {
        const float* actb = action + (size_t)b * NROWS;
        const float bvv = bv[0];
        const f32x2* w72v = (const f32x2*)(Wl + 72 * HID);  // uniform -> s_load
        const f32x2* wvv  = (const f32x2*)Wv;
#pragma unroll 1
        for (int i = 0; i < 4; i += 2) {
            const int naA = ces[i],     nbA = ced[i];
            const int naB = ces[i + 1], nbB = ced[i + 1];
            const float aA = actb[tid + i * TPB];
            const float aB = actb[tid + (i + 1) * TPB];
            const f32x2 avA = {aA, aA}, avB = {aB, aB};
            const float4* p1A = (const float4*)&qp0[naA * STR];
            const float4* p2A = (const float4*)&qp1[nbA * STR];
            const float4* p1B = (const float4*)&qp0[naB * STR];
            const float4* p2B = (const float4*)&qp1[nbB * STR];
            f32x2 vaccA = {0.f, 0.f}, vaccB = {0.f, 0.f};
#pragma unroll 2
            for (int q = 0; q < 8; q++) {
                const float4 paA = p1A[q], pbA = p2A[q];
                const float4 paB = p1B[q], pbB = p2B[q];
                const f32x2 rLA = relu2(lo2(paA) + lo2(pbA) + avA * w72v[2 * q]);
                const f32x2 rHA = relu2(hi2(paA) + hi2(pbA) + avA * w72v[2 * q + 1]);
                const f32x2 rLB = relu2(lo2(paB) + lo2(pbB) + avB * w72v[2 * q]);
                const f32x2 rHB = relu2(hi2(paB) + hi2(pbB) + avB * w72v[2 * q + 1]);
                vaccA += rLA * wvv[2 * q] + rHA * wvv[2 * q + 1];
                vaccB += rLB * wvv[2 * q] + rHB * wvv[2 * q + 1];
            }
            vsum += (bvv + vaccA.x + vaccA.y) + (bvv + vaccB.x + vaccB.y);
        }
        // factory rows 1024..1026 (na == nb)
        if (tid < NFACT) {
            const int r = NE + tid;
            const int na = NNODES - NFACT + tid;
            const float a = actb[r];
            const f32x2 av = {a, a};
            const float4* p1v = (const float4*)&qp0[na * STR];
            const float4* p2v = (const float4*)&qp1[na * STR];
            f32x2 vacc = {0.f, 0.f};
#pragma unroll 1
            for (int q = 0; q < 8; q++) {
                const float4 pa = p1v[q], pb = p2v[q];
                const f32x2 rL = relu2(lo2(pa) + lo2(pb) + av * w72v[2 * q]);
                const f32x2 rH = relu2(hi2(pa) + hi2(pb) + av * w72v[2 * q + 1]);
                vacc += rL * wvv[2 * q] + rH * wvv[2 * q + 1];
            }
            vsum += bvv + vacc.x + vacc.y;
        }
    }

    // ---- block reduction ----
#pragma unroll
    for (int off = 32; off > 0; off >>= 1)
        vsum += __shfl_down(vsum, off, 64);
    if ((tid & 63) == 0) wred[tid >> 6] = vsum;
    __syncthreads();
    if (tid == 0) {
        float t = 0.0f;
#pragma unroll
        for (int w = 0; w < TPB / 64; w++) t += wred[w];
        out[b] = t;
    }
}

extern "C" void kernel_launch(void* const* d_in, const int* in_sizes, int n_in,
                              void* d_out, int out_size, void* d_ws, size_t ws_size,
                              hipStream_t stream) {
    const float* x         = (const float*)d_in[0];
    const float* edge_attr = (const float*)d_in[2];
    const float* action    = (const float*)d_in[3];
    const int*   es        = (const int*)d_in[4];
    const int*   ed        = (const int*)d_in[5];
    const float* W1        = (const float*)d_in[6];
    const float* b1        = (const float*)d_in[7];
    const float* W2        = (const float*)d_in[8];
    const float* b2        = (const float*)d_in[9];
    const float* Wl        = (const float*)d_in[10];
    const float* bl        = (const float*)d_in[11];
    const float* Wv        = (const float*)d_in[12];
    const float* bv        = (const float*)d_in[13];
    float* out = (float*)d_out;

    critic_fused<<<dim3(out_size), dim3(TPB), 0, stream>>>(
        x, edge_attr, action, es, ed, W1, b1, W2, b2, Wl, bl, Wv, bv, out);
}